// Round 10
// baseline (512.681 us; speedup 1.0000x reference)
//
#include <hip/hip_runtime.h>
#include <hip/hip_bf16.h>

#define NN 8192
#define DD 128

typedef __attribute__((ext_vector_type(8))) short short8;
typedef __attribute__((ext_vector_type(4))) float f32x4;
typedef unsigned int u32;
typedef unsigned long long u64;
typedef unsigned char u8;

__device__ __forceinline__ ushort f2bf(float f) {
    __hip_bfloat16 h = __float2bfloat16(f);
    return *(ushort*)&h;
}
__device__ __forceinline__ u32 asu(float f) {
    union { float f; u32 i; } v; v.f = f; return v.i;
}
__device__ __forceinline__ float asf(u32 u) {
    union { u32 i; float f; } v; v.i = u; return v.f;
}

// ---------------- K0: pack A (int32 0/1) -> bitmask, fully coalesced ----------
// 2048 blocks x 256 thr; block covers 4 rows (32768 ints). Lane-contiguous
// int4 loads (1 KB/instr/wave), nibble -> LDS, coalesced u32 stores.
__global__ __launch_bounds__(256) void k0_pack(const int* __restrict__ A,
                                               u32* __restrict__ Abits) {
    __shared__ u8 ln[8192];
    int t = threadIdx.x;
    size_t base4 = (size_t)blockIdx.x * 8192;   // int4 units
    const int4* A4 = (const int4*)A;
#pragma unroll
    for (int j = 0; j < 32; ++j) {
        int u = j * 256 + t;
        int4 v = A4[base4 + u];
        u32 nib = (v.x ? 1u : 0u) | (v.y ? 2u : 0u) | (v.z ? 4u : 0u) | (v.w ? 8u : 0u);
        ln[u] = (u8)nib;
    }
    __syncthreads();
    const u64* l8 = (const u64*)ln;
#pragma unroll
    for (int j = 0; j < 4; ++j) {
        int w = j * 256 + t;
        u64 b = l8[w];
        u32 word = 0;
#pragma unroll
        for (int m = 0; m < 8; ++m)
            word |= ((u32)(b >> (8 * m)) & 0xFu) << (4 * m);
        Abits[blockIdx.x * 1024 + w] = word;
    }
}

// ---------------- K1f: Wh = X@Ws + transpose + per-row scalars ----------------
// ratio = e^{-0.8 s1} (softmax row-scale invariance); Epack = bf16(e^{s2}) |
// bf16(e^{0.2 s2})<<16.
__global__ __launch_bounds__(256) void k1_fused(
    const float* __restrict__ X, const float* __restrict__ Ws,
    const float* __restrict__ a, ushort* __restrict__ WhT,
    float* __restrict__ Rt, u32* __restrict__ Epack) {
    __shared__ float lWs[128 * 132];   // overlaid by lT[128][33] after use
    __shared__ float lX[32 * 132];
    __shared__ float la[256];
    int t = threadIdx.x, bx = blockIdx.x;
    int i0 = bx * 32;
    const float4* Ws4 = (const float4*)Ws;
    const float4* X4 = (const float4*)X;
    la[t] = a[t];
    for (int j = 0; j < 16; ++j) {
        int u = j * 256 + t;
        int k = u >> 5, c4 = u & 31;
        *(float4*)&lWs[k * 132 + c4 * 4] = Ws4[u];
    }
    for (int j = 0; j < 4; ++j) {
        int u = j * 256 + t;
        int r = u >> 5, c4 = u & 31;
        *(float4*)&lX[r * 132 + c4 * 4] = X4[bx * 1024 + u];
    }
    __syncthreads();
    int r0 = (t >> 5) * 4, c0 = (t & 31) * 4;
    float acc[4][4];
#pragma unroll
    for (int i = 0; i < 4; ++i)
#pragma unroll
        for (int j = 0; j < 4; ++j) acc[i][j] = 0.f;
#pragma unroll 4
    for (int k = 0; k < 128; ++k) {
        float4 wv = *(const float4*)&lWs[k * 132 + c0];
        float x0 = lX[(r0 + 0) * 132 + k];
        float x1 = lX[(r0 + 1) * 132 + k];
        float x2 = lX[(r0 + 2) * 132 + k];
        float x3 = lX[(r0 + 3) * 132 + k];
#pragma unroll
        for (int j = 0; j < 4; ++j) {
            acc[0][j] += x0 * ((const float*)&wv)[j];
            acc[1][j] += x1 * ((const float*)&wv)[j];
            acc[2][j] += x2 * ((const float*)&wv)[j];
            acc[3][j] += x3 * ((const float*)&wv)[j];
        }
    }
    __syncthreads();
    float* lT = lWs;   // [d=128][r=32] pad 33
#pragma unroll
    for (int i = 0; i < 4; ++i)
#pragma unroll
        for (int j = 0; j < 4; ++j) lT[(c0 + j) * 33 + r0 + i] = acc[i][j];
    __syncthreads();
    if (t < 128) {
        int r = t >> 2, q = t & 3;
        float s1 = 0.f, s2 = 0.f;
        for (int j = 0; j < 32; ++j) {
            int d = q * 32 + j;
            float v = lT[d * 33 + r];
            s1 += v * la[d];
            s2 += v * la[128 + d];
        }
        s1 += __shfl_xor(s1, 1); s1 += __shfl_xor(s1, 2);
        s2 += __shfl_xor(s2, 1); s2 += __shfl_xor(s2, 2);
        if (q == 0) {
            int i = i0 + r;
            Rt[i] = __expf(-0.8f * s1);
            Epack[i] = (u32)f2bf(__expf(s2)) | ((u32)f2bf(__expf(0.2f * s2)) << 16);
        }
    }
    int d = t >> 1, hf = t & 1;
    __attribute__((aligned(16))) ushort tmp[16];
#pragma unroll
    for (int s = 0; s < 16; ++s) tmp[s] = f2bf(lT[d * 33 + hf * 16 + s]);
    uint4* dst = (uint4*)&WhT[(size_t)d * NN + i0 + hf * 16];
    const uint4* srcv = (const uint4*)tmp;
    dst[0] = srcv[0];
    dst[1] = srcv[1];
}

__device__ __forceinline__ f32x4 mfma_bf16(short8 a, short8 b, f32x4 c) {
    return __builtin_amdgcn_mfma_f32_16x16x32_bf16(a, b, c, 0, 0, 0);
}

// ---------------- K3: masked-softmax GEMM, thin blocks, high TLP --------------
// grid (256 rowblocks of 32, 8 ksplit of 1024) x 256 thr (4 waves: g=wv&1
// rowgroup of 16, h=wv>>1 col-half of 64). Zero HBM in-loop (Abits/WhT are
// L2/L3-resident). Bits distance-1 prefetch; E bf16-packed in 4 KB LDS; no
// in-loop barrier; row sums via ones-MFMA on h==0 waves.
__global__ __launch_bounds__(256, 5) void k3_main(
    const u32* __restrict__ Abits, const ushort* __restrict__ WhT,
    const float* __restrict__ Rt, const u32* __restrict__ Epack,
    float* __restrict__ Hp, float* __restrict__ Lp) {

    __shared__ u32 lE[1024];   // 4 KB

    int tid = threadIdx.x;
    int lane = tid & 63;
    int wv = tid >> 6;
    int g = wv & 1;
    int h = wv >> 1;
    int n = lane & 15;
    int kg = lane >> 4;
    int kgs = kg * 8;

    int bx = blockIdx.x;
    int kb = blockIdx.y;
    int row = bx * 32 + g * 16 + n;
    int kbase = kb * 1024;

#pragma unroll
    for (int j = 0; j < 4; ++j) lE[j * 256 + tid] = Epack[kbase + j * 256 + tid];

    float ratio = Rt[row];
    const u64* Arow = (const u64*)Abits + (size_t)row * 128 + kb * 16;
    const ushort* Bc0 = WhT + (size_t)(h * 64 +  0 + n) * NN + kbase + kgs;
    const ushort* Bc1 = WhT + (size_t)(h * 64 + 16 + n) * NN + kbase + kgs;
    const ushort* Bc2 = WhT + (size_t)(h * 64 + 32 + n) * NN + kbase + kgs;
    const ushort* Bc3 = WhT + (size_t)(h * 64 + 48 + n) * NN + kbase + kgs;

    short8 ones;
#pragma unroll
    for (int j = 0; j < 8; ++j) ones[j] = (short)0x3F80;

    f32x4 acc0 = (f32x4){0.f, 0.f, 0.f, 0.f};
    f32x4 acc1 = (f32x4){0.f, 0.f, 0.f, 0.f};
    f32x4 acc2 = (f32x4){0.f, 0.f, 0.f, 0.f};
    f32x4 acc3 = (f32x4){0.f, 0.f, 0.f, 0.f};
    f32x4 accl = (f32x4){0.f, 0.f, 0.f, 0.f};

    __syncthreads();   // lE ready (only barrier)

    u64 bitsA = Arow[0];

    for (int kt = 0; kt < 16; ++kt) {
        int ko = kt * 64;
        short8 B0 = *(const short8*)(Bc0 + ko);
        short8 B1 = *(const short8*)(Bc1 + ko);
        short8 B2 = *(const short8*)(Bc2 + ko);
        short8 B3 = *(const short8*)(Bc3 + ko);
        short8 B4 = *(const short8*)(Bc0 + ko + 32);
        short8 B5 = *(const short8*)(Bc1 + ko + 32);
        short8 B6 = *(const short8*)(Bc2 + ko + 32);
        short8 B7 = *(const short8*)(Bc3 + ko + 32);
        u64 bn = (kt < 15) ? Arow[kt + 1] : 0;
        u32 lo = (u32)bitsA, hi = (u32)(bitsA >> 32);
#pragma unroll
        for (int tp = 0; tp < 2; ++tp) {
            int ke = ko + tp * 32 + kgs;
            u32 ev[8];
            *(uint4*)(ev)     = *(const uint4*)&lE[ke];
            *(uint4*)(ev + 4) = *(const uint4*)&lE[ke + 4];
            u32 byte = ((tp ? hi : lo) >> kgs) & 0xFFu;
            u32 wb[8];
#pragma unroll
            for (int u = 0; u < 8; ++u) {
                float ep = asf(ev[u] << 16);
                float en = asf(ev[u] & 0xFFFF0000u);
                float w = fmaxf(ep, ratio * en);
                w = (byte & (1u << u)) ? w : 0.f;
                wb[u] = asu(w);
            }
            short8 af;
#pragma unroll
            for (int p = 0; p < 4; ++p)
                ((u32*)&af)[p] = __builtin_amdgcn_perm(wb[2 * p + 1], wb[2 * p], 0x07060302);
            acc0 = mfma_bf16(af, tp ? B4 : B0, acc0);
            acc1 = mfma_bf16(af, tp ? B5 : B1, acc1);
            acc2 = mfma_bf16(af, tp ? B6 : B2, acc2);
            acc3 = mfma_bf16(af, tp ? B7 : B3, acc3);
            if (h == 0) accl = mfma_bf16(af, ones, accl);
        }
        bitsA = bn;
    }

    // epilogue. C/D layout: col = lane&15, row = (lane>>4)*4 + reg  [m89]
    if (h == 0 && n == 0) {
#pragma unroll
        for (int r = 0; r < 4; ++r)
            Lp[(size_t)kb * NN + bx * 32 + g * 16 + kg * 4 + r] = accl[r];
    }
    float* Hpb = Hp + (size_t)kb * (NN * DD);
#pragma unroll
    for (int r = 0; r < 4; ++r) {
        int orow = bx * 32 + g * 16 + kg * 4 + r;
        Hpb[(size_t)orow * DD + h * 64 + n]      = acc0[r];
        Hpb[(size_t)orow * DD + h * 64 + 16 + n] = acc1[r];
        Hpb[(size_t)orow * DD + h * 64 + 32 + n] = acc2[r];
        Hpb[(size_t)orow * DD + h * 64 + 48 + n] = acc3[r];
    }
}

// ---------------- K4: combine 8 split-K partials, normalize ----------------
__global__ void k4_final(const float* __restrict__ Hp, const float* __restrict__ Lp,
                         float* __restrict__ out) {
    int idx = blockIdx.x * 256 + threadIdx.x;
    int i = idx >> 7;
    float sv = 0.f, l = 0.f;
#pragma unroll
    for (int p = 0; p < 8; ++p) {
        sv += Hp[(size_t)p * 1048576 + idx];
        l  += Lp[p * 8192 + i];
    }
    out[idx] = sv / l;
}

extern "C" void kernel_launch(void* const* d_in, const int* in_sizes, int n_in,
                              void* d_out, int out_size, void* d_ws, size_t ws_size,
                              hipStream_t stream) {
    const int*   A  = (const int*)d_in[0];
    const float* X  = (const float*)d_in[1];
    const float* Ws = (const float*)d_in[2];
    const float* a  = (const float*)d_in[3];
    float* out = (float*)d_out;

    char* ws = (char*)d_ws;
    u32*    Abits = (u32*)(ws);                            // 8 MB
    ushort* WhT   = (ushort*)(ws + (8u << 20));            // 2 MB
    float*  Rt    = (float*)(ws + (10u << 20));            // 32 KB
    u32*    Epack = (u32*)(ws + (10u << 20) + (32u << 10)); // 32 KB
    float*  Lp    = (float*)(ws + (10u << 20) + (64u << 10)); // 256 KB
    float*  Hp    = (float*)(ws + (12u << 20));            // 32 MB (8 partials)

    k0_pack<<<2048, 256, 0, stream>>>(A, Abits);
    k1_fused<<<256, 256, 0, stream>>>(X, Ws, a, WhT, Rt, Epack);
    k3_main<<<dim3(256, 8), 256, 0, stream>>>(Abits, WhT, Rt, Epack, Hp, Lp);
    k4_final<<<4096, 256, 0, stream>>>(Hp, Lp, out);
}